// Round 1
// baseline (599.396 us; speedup 1.0000x reference)
//
#include <hip/hip_runtime.h>

// IoU elementwise kernel — memory-bound streaming.
// Layouts: cell_nos [N,2] i32, output [N,5,5] f32, target [N,5] f32,
// out [N,5] f32. One block = 256 boxes; LDS-staged coalesced IO.

#define YI 20.0f
#define BOXES_PER_BLK 256

__global__ __launch_bounds__(256) void iou_kernel(
    const int*   __restrict__ cell,
    const float* __restrict__ outp,
    const float* __restrict__ tgt,
    float*       __restrict__ dst,
    int nboxes)
{
    __shared__ float s_out[BOXES_PER_BLK * 25];   // 25600 B
    __shared__ float s_tgt[BOXES_PER_BLK * 5];    //  5120 B (reused for results)
    __shared__ int   s_cell[BOXES_PER_BLK * 2];   //  2048 B

    const int t = threadIdx.x;
    const long long base = (long long)blockIdx.x * BOXES_PER_BLK;
    const bool full_block = (base + BOXES_PER_BLK) <= (long long)nboxes;  // block-uniform

    if (full_block) {
        // ---- stage global -> LDS, fully coalesced float4/int4 ----
        {
            const float4* g = reinterpret_cast<const float4*>(outp + base * 25); // 16B aligned
            float4* s = reinterpret_cast<float4*>(s_out);
            #pragma unroll
            for (int i = t; i < (BOXES_PER_BLK * 25) / 4; i += BOXES_PER_BLK) s[i] = g[i];
        }
        {
            const float4* g = reinterpret_cast<const float4*>(tgt + base * 5);
            float4* s = reinterpret_cast<float4*>(s_tgt);
            #pragma unroll
            for (int i = t; i < (BOXES_PER_BLK * 5) / 4; i += BOXES_PER_BLK) s[i] = g[i];
        }
        {
            const int4* g = reinterpret_cast<const int4*>(cell + base * 2);
            int4* s = reinterpret_cast<int4*>(s_cell);
            if (t < (BOXES_PER_BLK * 2) / 4) s[t] = g[t];
        }
        __syncthreads();

        // ---- compute: thread t owns box (base + t) ----
        const float* my_out = &s_out[t * 25];
        const float* my_tgt = &s_tgt[t * 5];
        const float ci = (float)s_cell[t * 2 + 0];
        const float cj = (float)s_cell[t * 2 + 1];
        const float cic = ci * YI + 0.5f * YI;
        const float cjc = cj * YI + 0.5f * YI;

        // ground-truth box
        const float dxg = my_tgt[1], dyg = my_tgt[2];
        const float hg = my_tgt[3] * YI, wg = my_tgt[4] * YI;
        const float xcg = cic + dxg * YI, ycg = cjc + dyg * YI;
        const float x1g = ycg - 0.5f * wg, y1g = xcg - 0.5f * hg;
        const float x2g = ycg + 0.5f * wg, y2g = xcg + 0.5f * hg;
        const float area_g = (x2g - x1g) * (y2g - y1g);

        float res[5];
        #pragma unroll
        for (int a = 0; a < 5; ++a) {
            const float dx = my_out[5 * a + 1], dy = my_out[5 * a + 2];
            const float h = my_out[5 * a + 3] * YI, w = my_out[5 * a + 4] * YI;
            const float xc = cic + dx * YI, yc = cjc + dy * YI;
            const float x1 = yc - 0.5f * w, y1 = xc - 0.5f * h;
            const float x2 = yc + 0.5f * w, y2 = xc + 0.5f * h;
            const float area_p = (x2 - x1) * (y2 - y1);
            const float ltx = fmaxf(x1, x1g), lty = fmaxf(y1, y1g);
            const float rbx = fminf(x2, x2g), rby = fminf(y2, y2g);
            const float wx = fmaxf(rbx - ltx, 0.0f), wy = fmaxf(rby - lty, 0.0f);
            const float inter = wx * wy;
            const float uni = area_p + area_g - inter;
            res[a] = inter / uni;
        }

        // thread t only reads/writes its own s_tgt slice -> no barrier needed here
        #pragma unroll
        for (int a = 0; a < 5; ++a) s_tgt[t * 5 + a] = res[a];
        __syncthreads();

        // ---- coalesced float4 store of the result tile ----
        {
            float4* g = reinterpret_cast<float4*>(dst + base * 5);
            const float4* s = reinterpret_cast<const float4*>(s_tgt);
            #pragma unroll
            for (int i = t; i < (BOXES_PER_BLK * 5) / 4; i += BOXES_PER_BLK) g[i] = s[i];
        }
    } else {
        // tail path (not taken for N = 4,000,000, kept for safety): scalar, guarded
        const long long n = base + t;
        if (n < (long long)nboxes) {
            const float ci = (float)cell[n * 2 + 0];
            const float cj = (float)cell[n * 2 + 1];
            const float cic = ci * YI + 0.5f * YI;
            const float cjc = cj * YI + 0.5f * YI;
            const float dxg = tgt[n * 5 + 1], dyg = tgt[n * 5 + 2];
            const float hg = tgt[n * 5 + 3] * YI, wg = tgt[n * 5 + 4] * YI;
            const float xcg = cic + dxg * YI, ycg = cjc + dyg * YI;
            const float x1g = ycg - 0.5f * wg, y1g = xcg - 0.5f * hg;
            const float x2g = ycg + 0.5f * wg, y2g = xcg + 0.5f * hg;
            const float area_g = (x2g - x1g) * (y2g - y1g);
            for (int a = 0; a < 5; ++a) {
                const float dx = outp[n * 25 + 5 * a + 1], dy = outp[n * 25 + 5 * a + 2];
                const float h = outp[n * 25 + 5 * a + 3] * YI, w = outp[n * 25 + 5 * a + 4] * YI;
                const float xc = cic + dx * YI, yc = cjc + dy * YI;
                const float x1 = yc - 0.5f * w, y1 = xc - 0.5f * h;
                const float x2 = yc + 0.5f * w, y2 = xc + 0.5f * h;
                const float area_p = (x2 - x1) * (y2 - y1);
                const float ltx = fmaxf(x1, x1g), lty = fmaxf(y1, y1g);
                const float rbx = fminf(x2, x2g), rby = fminf(y2, y2g);
                const float wx = fmaxf(rbx - ltx, 0.0f), wy = fmaxf(rby - lty, 0.0f);
                const float inter = wx * wy;
                const float uni = area_p + area_g - inter;
                dst[n * 5 + a] = inter / uni;
            }
        }
    }
}

extern "C" void kernel_launch(void* const* d_in, const int* in_sizes, int n_in,
                              void* d_out, int out_size, void* d_ws, size_t ws_size,
                              hipStream_t stream) {
    const int*   cell = (const int*)d_in[0];    // [N,2] int32
    const float* outp = (const float*)d_in[1];  // [N,5,5] f32
    const float* tgt  = (const float*)d_in[2];  // [N,5] f32
    float*       dst  = (float*)d_out;          // [N,5] f32

    const int nboxes = in_sizes[0] / 2;
    const int grid = (nboxes + BOXES_PER_BLK - 1) / BOXES_PER_BLK;  // 15625 for N=4M
    iou_kernel<<<grid, BOXES_PER_BLK, 0, stream>>>(cell, outp, tgt, dst, nboxes);
}

// Round 2
// 592.120 us; speedup vs baseline: 1.0123x; 1.0123x over previous
//
#include <hip/hip_runtime.h>

// IoU elementwise — pure streaming, one thread per output element (n, a).
// Layouts: cell_nos [N,2] i32, output [N,5,5] f32, target [N,5] f32,
// out [N,5] f32. No LDS, no barriers: 3 independent load streams per
// thread, fully-coalesced scalar store. HBM-bound (592 MB total traffic).

#define YI 20.0f

__global__ __launch_bounds__(256) void iou_elem(
    const int*   __restrict__ cell,
    const float* __restrict__ outp,
    const float* __restrict__ tgt,
    float*       __restrict__ dst,
    int total)   // = N * 5
{
    const int tid = blockIdx.x * 256 + threadIdx.x;
    if (tid >= total) return;

    const unsigned n = (unsigned)tid / 5u;        // magic-mul, no HW div
    const unsigned a = (unsigned)tid - 5u * n;

    // --- independent loads (issue all before any use) ---
    const float* op = outp + (size_t)n * 25 + (size_t)a * 5;
    const float dx = op[1];
    const float dy = op[2];
    const float hr = op[3];
    const float wr = op[4];

    const float* tp = tgt + (size_t)n * 5;
    const float dxg = tp[1];
    const float dyg = tp[2];
    const float hgr = tp[3];
    const float wgr = tp[4];

    const int2 c = reinterpret_cast<const int2*>(cell)[n];  // 8B aligned dwordx2

    // --- compute (mirrors reference math exactly) ---
    const float cic = (float)c.x * YI + 0.5f * YI;
    const float cjc = (float)c.y * YI + 0.5f * YI;

    // ground-truth box
    const float hg = hgr * YI, wg = wgr * YI;
    const float xcg = cic + dxg * YI, ycg = cjc + dyg * YI;
    const float x1g = ycg - 0.5f * wg, y1g = xcg - 0.5f * hg;
    const float x2g = ycg + 0.5f * wg, y2g = xcg + 0.5f * hg;
    const float area_g = (x2g - x1g) * (y2g - y1g);

    // predicted box (anchor a)
    const float h = hr * YI, w = wr * YI;
    const float xc = cic + dx * YI, yc = cjc + dy * YI;
    const float x1 = yc - 0.5f * w, y1 = xc - 0.5f * h;
    const float x2 = yc + 0.5f * w, y2 = xc + 0.5f * h;
    const float area_p = (x2 - x1) * (y2 - y1);

    const float ltx = fmaxf(x1, x1g), lty = fmaxf(y1, y1g);
    const float rbx = fminf(x2, x2g), rby = fminf(y2, y2g);
    const float wx = fmaxf(rbx - ltx, 0.0f), wy = fmaxf(rby - lty, 0.0f);
    const float inter = wx * wy;
    const float uni = area_p + area_g - inter;

    dst[tid] = inter / uni;   // coalesced scalar store
}

extern "C" void kernel_launch(void* const* d_in, const int* in_sizes, int n_in,
                              void* d_out, int out_size, void* d_ws, size_t ws_size,
                              hipStream_t stream) {
    const int*   cell = (const int*)d_in[0];    // [N,2] int32
    const float* outp = (const float*)d_in[1];  // [N,5,5] f32
    const float* tgt  = (const float*)d_in[2];  // [N,5] f32
    float*       dst  = (float*)d_out;          // [N,5] f32

    const int total = out_size;                 // N * 5 = 20,000,000
    const int grid = (total + 255) / 256;       // 78,125
    iou_elem<<<grid, 256, 0, stream>>>(cell, outp, tgt, dst, total);
}